// Round 2
// baseline (1676.665 us; speedup 1.0000x reference)
//
#include <hip/hip_runtime.h>
#include <hip/hip_bf16.h>

#define T_LEN 200
#define F_IN 64
#define A_IN 128
#define H 100
#define H4 400
#define OUT_N 10
#define ROWS 8
#define ZSTR 404   // 8-row z buffer stride; 404 -> conflict-free scatter (16*lg + ln15)

typedef __attribute__((ext_vector_type(8))) short bf16x8;
typedef __attribute__((ext_vector_type(4))) float f32x4;

__device__ __forceinline__ unsigned short f2bf(float f) {
    union { float f; unsigned u; } v; v.f = f;
    unsigned r = v.u + 0x7FFFu + ((v.u >> 16) & 1u);
    return (unsigned short)(r >> 16);
}

// 2x f32 -> packed bf16 pair (RNE), single instruction on gfx950
__device__ __forceinline__ unsigned cvtpk(float lo, float hi) {
    unsigned r;
    asm("v_cvt_pk_bf16_f32 %0, %1, %2" : "=v"(r) : "v"(lo), "v"(hi));
    return r;
}

__device__ __forceinline__ float sigm(float x) {
    return 1.0f / (1.0f + __expf(-x));
}

extern "C" __global__ void __launch_bounds__(512, 4)
traj_kernel(const float* __restrict__ attrs, const float* __restrict__ seq,
            const float* __restrict__ Wd, const float* __restrict__ bd,
            const float* __restrict__ Wk, const float* __restrict__ Wr,
            const float* __restrict__ bl, const float* __restrict__ W1,
            const float* __restrict__ b1, const float* __restrict__ W2,
            const float* __restrict__ b2, const float* __restrict__ Wc,
            const float* __restrict__ bc, float* __restrict__ out)
{
    // LDS map (bytes), total 20224:
    //   [0, 12928)      zb   float[8][404]    z exchange (rows 0..7 only)
    //   [12928, 17024)  hl   ushort[4][64][8] h bf16 A-fragments (rows >=8 stay 0)
    //   [17024, 20224)  h32  float[8][100]    final h fp32
    // epilogue aliases (loop-dead regions):
    //   att [8][136] @0, catb [8][204] @4352, x1b [8][100] @10880,
    //   x2b [8][50] @14080, lgb [8][10] @15680   (all below h32 @17024)
    __shared__ __align__(16) char smem[20224];
    float* zb = (float*)smem;
    unsigned short* hl = (unsigned short*)(smem + 12928);
    float* h32 = (float*)(smem + 17024);

    const int tid = threadIdx.x;
    const int lane = tid & 63;
    const int w = tid >> 6;
    const int ln15 = lane & 15;
    const int lg = lane >> 4;
    const int b0 = blockIdx.x * ROWS;

    // n-tiles: waves 0..6 get 3 tiles, wave 7 gets 4 (wave 7 is idle in gate k=1)
    const int nt0 = 3 * w;
    const int ntc = (w == 7) ? 4 : 3;

    // ---- pack weight B-fragments into registers (one-time) ----
    // B-frag (16x16x32): lane holds col n = lane&15, k = (lane>>4)*8 + i
    bf16x8 wkf[4][2];
    bf16x8 wrf[4][4];
#pragma unroll
    for (int q = 0; q < 4; q++) {
        const bool v = (q < ntc);
        const int n = v ? ((nt0 + q) * 16 + ln15) : 0;
#pragma unroll
        for (int kt = 0; kt < 2; kt++) {
            bf16x8 f;
#pragma unroll
            for (int i = 0; i < 8; i++) {
                int k = kt * 32 + lg * 8 + i;
                float x = v ? Wk[k * H4 + n] : 0.0f;
                f[i] = (short)f2bf(x);
            }
            wkf[q][kt] = f;
        }
#pragma unroll
        for (int kt = 0; kt < 4; kt++) {
            bf16x8 f;
#pragma unroll
            for (int i = 0; i < 8; i++) {
                int k = kt * 32 + lg * 8 + i;
                float x = (v && k < H) ? Wr[k * H4 + n] : 0.0f;  // zero-pad k=100..127
                f[i] = (short)f2bf(x);
            }
            wrf[q][kt] = f;
        }
    }

    // ---- gate-thread state: element e = tid + 512*k, e < 800; b = e&7, j = e>>3 ----
    float bi0[2], bf0[2], bg0[2], bo0[2], creg[2];
    int zoff[2], hoff[2], h32off[2];
    bool act[2];
#pragma unroll
    for (int k = 0; k < 2; k++) {
        creg[k] = 0.0f;
        int e = tid + 512 * k;
        act[k] = (e < ROWS * H);
        int b = act[k] ? (e & 7) : 0;
        int j = act[k] ? (e >> 3) : 0;
        zoff[k] = b * ZSTR + j;
        // h A-frag position: ktile = j>>5, frag-lane = b + 16*((j>>3)&3), elem = j&7
        hoff[k] = ((j >> 5) * 64 + (b + 16 * ((j >> 3) & 3))) * 8 + (j & 7);
        h32off[k] = b * H + j;
        if (act[k]) {
            bi0[k] = bl[j]; bf0[k] = bl[H + j]; bg0[k] = bl[2 * H + j]; bo0[k] = bl[3 * H + j];
        } else { bi0[k] = 0; bf0[k] = 0; bg0[k] = 0; bo0[k] = 0; }
    }

    // zero h fragments (rows >=8 and k>=100 padding stay zero forever)
    for (int i = tid; i < 4 * 64 * 8; i += 512) hl[i] = 0;
    __syncthreads();

    // seq A-frag addressing: lane holds row = ln15 (clamped; rows 8..15 are junk,
    // they only feed acc rows 8..15 which are never read), k(feature) = lg*8 + i
    int brow = b0 + ln15; if (brow > 4095) brow = 4095;
    const float* sp = seq + (size_t)brow * (T_LEN * F_IN) + lg * 8;

    f32x4 s0 = *(const f32x4*)(sp);
    f32x4 s1 = *(const f32x4*)(sp + 4);
    f32x4 s2 = *(const f32x4*)(sp + 32);
    f32x4 s3 = *(const f32x4*)(sp + 36);
    sp += F_IN;

    // LDS pointers hoisted out of the loop
    const unsigned short* hp = hl + lane * 8;
    float* zwr = zb + (lg * 4) * ZSTR;   // valid only for lg<2

    for (int t = 0; t < T_LEN; t++) {
        // seq floats -> bf16 A-fragments via v_cvt_pk (1 instr / 2 elems)
        union { unsigned u[4]; bf16x8 v; } ua, ub;
        ua.u[0] = cvtpk(s0[0], s0[1]); ua.u[1] = cvtpk(s0[2], s0[3]);
        ua.u[2] = cvtpk(s1[0], s1[1]); ua.u[3] = cvtpk(s1[2], s1[3]);
        ub.u[0] = cvtpk(s2[0], s2[1]); ub.u[1] = cvtpk(s2[2], s2[3]);
        ub.u[2] = cvtpk(s3[0], s3[1]); ub.u[3] = cvtpk(s3[2], s3[3]);
        bf16x8 a0 = ua.v, a1 = ub.v;

        // load h(t-1) fragments (all waves read the same 4 KB)
        bf16x8 hf0 = *(const bf16x8*)(hp + 0 * 512);
        bf16x8 hf1 = *(const bf16x8*)(hp + 1 * 512);
        bf16x8 hf2 = *(const bf16x8*)(hp + 2 * 512);
        bf16x8 hf3 = *(const bf16x8*)(hp + 3 * 512);

        // prefetch seq tile for t+1 (returns under MFMA + gate phases)
        if (t < T_LEN - 1) {
            s0 = *(const f32x4*)(sp);
            s1 = *(const f32x4*)(sp + 4);
            s2 = *(const f32x4*)(sp + 32);
            s3 = *(const f32x4*)(sp + 36);
            sp += F_IN;
        }

        // z = seq_t @ Wk + h @ Wr
        f32x4 acc[4];
        __builtin_amdgcn_s_setprio(1);
#pragma unroll
        for (int q = 0; q < 4; q++) {
            if (q < ntc) {
                f32x4 a = {0.f, 0.f, 0.f, 0.f};
                a = __builtin_amdgcn_mfma_f32_16x16x32_bf16(a0,  wkf[q][0], a, 0, 0, 0);
                a = __builtin_amdgcn_mfma_f32_16x16x32_bf16(a1,  wkf[q][1], a, 0, 0, 0);
                a = __builtin_amdgcn_mfma_f32_16x16x32_bf16(hf0, wrf[q][0], a, 0, 0, 0);
                a = __builtin_amdgcn_mfma_f32_16x16x32_bf16(hf1, wrf[q][1], a, 0, 0, 0);
                a = __builtin_amdgcn_mfma_f32_16x16x32_bf16(hf2, wrf[q][2], a, 0, 0, 0);
                a = __builtin_amdgcn_mfma_f32_16x16x32_bf16(hf3, wrf[q][3], a, 0, 0, 0);
                acc[q] = a;
            }
        }
        __builtin_amdgcn_s_setprio(0);

        // scatter useful z rows (D row = lg*4+r; only rows 0..7 -> lg<2).
        // banks = 16*lg + ln15 + c -> conflict-free over the 32 active lanes
        if (lg < 2) {
#pragma unroll
            for (int q = 0; q < 4; q++) {
                if (q < ntc) {
                    const int col = (nt0 + q) * 16 + ln15;
#pragma unroll
                    for (int r = 0; r < 4; r++) zwr[r * ZSTR + col] = acc[q][r];
                }
            }
        }
        __syncthreads();

        // gate phase (fp32)
        const bool last = (t == T_LEN - 1);
#pragma unroll
        for (int k = 0; k < 2; k++) {
            if (act[k]) {
                float zi = zb[zoff[k]]         + bi0[k];
                float zf = zb[zoff[k] + H]     + bf0[k];
                float zg = zb[zoff[k] + 2 * H] + bg0[k];
                float zo = zb[zoff[k] + 3 * H] + bo0[k];
                float ii = sigm(zi), ff = sigm(zf), oo = sigm(zo);
                float gg = fmaxf(zg, 0.0f);
                float c = ff * creg[k] + ii * gg;
                creg[k] = c;
                float h = oo * fmaxf(c, 0.0f);
                hl[hoff[k]] = f2bf(h);
                if (last) h32[h32off[k]] = h;
            }
        }
        __syncthreads();
    }

    // ---- epilogue: fp32 dense chain + softmax (tiny) ----
    float* att  = (float*)smem;            // [8][136] (136: 16B-aligned rows, 2-way banks)
    float* catb = (float*)(smem + 4352);   // [8][204]
    float* x1b  = (float*)(smem + 10880);  // [8][100]
    float* x2b  = (float*)(smem + 14080);  // [8][50]
    float* lgb  = (float*)(smem + 15680);  // [8][10]

    if (tid < 256) {
        f32x4 v = ((const f32x4*)(attrs + (size_t)b0 * A_IN))[tid];
        int row = tid >> 5, c4 = tid & 31;
        *(f32x4*)(att + row * 136 + c4 * 4) = v;
    }
    __syncthreads();

#pragma unroll
    for (int k = 0; k < 2; k++) {
        int e = tid + 512 * k;
        if (e < ROWS * H) {
            int b = e & 7, j = e >> 3;
            float s = bd[j];
            for (int kk = 0; kk < A_IN; kk++) s += att[b * 136 + kk] * Wd[kk * H + j];
            catb[b * 204 + j] = fmaxf(s, 0.0f);
            catb[b * 204 + H + j] = h32[b * H + j];
        }
    }
    __syncthreads();

#pragma unroll
    for (int k = 0; k < 2; k++) {
        int e = tid + 512 * k;
        if (e < ROWS * H) {
            int b = e & 7, j = e >> 3;
            float s = b1[j];
            for (int kk = 0; kk < 200; kk++) s += catb[b * 204 + kk] * W1[kk * H + j];
            x1b[b * H + j] = fmaxf(s, 0.0f);
        }
    }
    __syncthreads();

    if (tid < ROWS * 50) {
        int b = tid & 7, j = tid >> 3;
        float s = b2[j];
        for (int kk = 0; kk < H; kk++) s += x1b[b * H + kk] * W2[kk * 50 + j];
        x2b[b * 50 + j] = fmaxf(s, 0.0f);
    }
    __syncthreads();

    if (tid < ROWS * OUT_N) {
        int b = tid / OUT_N, o = tid % OUT_N;
        float s = bc[o];
        for (int kk = 0; kk < 50; kk++) s += x2b[b * 50 + kk] * Wc[kk * OUT_N + o];
        lgb[b * OUT_N + o] = s;
    }
    __syncthreads();

    if (tid < ROWS) {
        int b = tid;
        float m = -1e30f, v[10];
#pragma unroll
        for (int o = 0; o < 10; o++) { v[o] = lgb[b * 10 + o]; m = fmaxf(m, v[o]); }
        float ssum = 0.0f;
#pragma unroll
        for (int o = 0; o < 10; o++) { v[o] = __expf(v[o] - m); ssum += v[o]; }
        float inv = 1.0f / ssum;
#pragma unroll
        for (int o = 0; o < 10; o++) out[(size_t)(b0 + b) * 10 + o] = v[o] * inv;
    }
}

extern "C" void kernel_launch(void* const* d_in, const int* in_sizes, int n_in,
                              void* d_out, int out_size, void* d_ws, size_t ws_size,
                              hipStream_t stream) {
    const float* attrs = (const float*)d_in[0];
    const float* seq   = (const float*)d_in[1];
    const float* Wd    = (const float*)d_in[2];
    const float* bd    = (const float*)d_in[3];
    const float* Wk    = (const float*)d_in[4];
    const float* Wr    = (const float*)d_in[5];
    const float* bl    = (const float*)d_in[6];
    const float* W1    = (const float*)d_in[7];
    const float* b1    = (const float*)d_in[8];
    const float* W2    = (const float*)d_in[9];
    const float* b2    = (const float*)d_in[10];
    const float* Wc    = (const float*)d_in[11];
    const float* bc    = (const float*)d_in[12];
    float* out = (float*)d_out;

    hipLaunchKernelGGL(traj_kernel, dim3(512), dim3(512), 0, stream,
                       attrs, seq, Wd, bd, Wk, Wr, bl, W1, b1, W2, b2, Wc, bc, out);
}

// Round 3
// 363.687 us; speedup vs baseline: 4.6102x; 4.6102x over previous
//
#include <hip/hip_runtime.h>
#include <hip/hip_bf16.h>

#define T_LEN 200
#define F_IN 64
#define A_IN 128
#define H 100
#define H4 400
#define OUT_N 10
#define ROWS 16
#define ZSTR 404   // 404 mod 8 == 4 -> scatter 2-way (free); gate reads 2-way (free)

typedef __attribute__((ext_vector_type(8))) short bf16x8;
typedef __attribute__((ext_vector_type(4))) float f32x4;

__device__ __forceinline__ unsigned short f2bf(float f) {
    union { float f; unsigned u; } v; v.f = f;
    unsigned r = v.u + 0x7FFFu + ((v.u >> 16) & 1u);
    return (unsigned short)(r >> 16);
}

// 2x f32 -> packed bf16 (RNE), single instruction
__device__ __forceinline__ unsigned cvtpk(float lo, float hi) {
    unsigned r;
    asm("v_cvt_pk_bf16_f32 %0, %1, %2" : "=v"(r) : "v"(lo), "v"(hi));
    return r;
}

__device__ __forceinline__ float sigm(float x) {
    return 1.0f / (1.0f + __expf(-x));
}

extern "C" __global__ void __launch_bounds__(512, 2)
traj_kernel(const float* __restrict__ attrs, const float* __restrict__ seq,
            const float* __restrict__ Wd, const float* __restrict__ bd,
            const float* __restrict__ Wk, const float* __restrict__ Wr,
            const float* __restrict__ bl, const float* __restrict__ W1,
            const float* __restrict__ b1, const float* __restrict__ W2,
            const float* __restrict__ b2, const float* __restrict__ Wc,
            const float* __restrict__ bc, float* __restrict__ out)
{
    // LDS map (bytes), total 36352:
    //   [0, 25856)       zb   float[16][404]
    //   [25856, 29952)   hl   ushort[4][64][8]  h bf16 A-fragments
    //   [29952, 36352)   h32  float[16][100]    final h fp32
    // epilogue aliases (loop-dead): att [16][128]@0, catb [16][200]@8192,
    //   x1b [16][100]@20992 (overlaps dead hl), x2b [16][50]@0, lgb [16][10]@3200
    __shared__ __align__(16) char smem[36352];
    float* zb = (float*)smem;
    unsigned short* hl = (unsigned short*)(smem + 25856);
    float* h32 = (float*)(smem + 29952);

    const int tid = threadIdx.x;
    const int lane = tid & 63;
    const int w = tid >> 6;
    const int ln15 = lane & 15;
    const int lg = lane >> 4;
    const int b0 = blockIdx.x * ROWS;

    // n-tiles: waves 0..6 own {3w,3w+1,3w+2}; wave 7 owns {21,22,23,24}
    const int nt0 = 3 * w;
    const int ntc = (w == 7) ? 4 : 3;
    const bool w7 = (w == 7);
    const bool w0 = (w == 0);

    // ---- one-time weight B-fragment packing (B-frag: col=lane&15, k=(lane>>4)*8+i)
    bf16x8 wkf[4][2];
    bf16x8 wrf[4][4];
    float blf[4];
#pragma unroll
    for (int q = 0; q < 4; q++) {
        const bool v = (q < ntc);
        const int n = v ? ((nt0 + q) * 16 + ln15) : 0;
        blf[q] = v ? bl[n] : 0.0f;
#pragma unroll
        for (int kt = 0; kt < 2; kt++) {
            bf16x8 f;
#pragma unroll
            for (int i = 0; i < 8; i++) {
                int k = kt * 32 + lg * 8 + i;
                f[i] = (short)f2bf(v ? Wk[k * H4 + n] : 0.0f);
            }
            wkf[q][kt] = f;
        }
#pragma unroll
        for (int kt = 0; kt < 4; kt++) {
            bf16x8 f;
#pragma unroll
            for (int i = 0; i < 8; i++) {
                int k = kt * 32 + lg * 8 + i;
                f[i] = (short)f2bf((v && k < H) ? Wr[k * H4 + n] : 0.0f);
            }
            wrf[q][kt] = f;
        }
    }

    // ---- gate slots: e0=tid, e1=tid+512, e2=tid+1024 (all<1536), e3=tid+1536 (w0 only)
    const int b_0 = tid & 15,          j_0 = tid >> 4;
    const int b_1 = b_0,               j_1 = (tid + 512) >> 4;
    const int b_2 = b_0,               j_2 = (tid + 1024) >> 4;
    const int b_3 = b_0,               j_3 = (tid + 1536) >> 4;
#define HOFF(b, j) ((((j) >> 5) * 64 + ((b) + 16 * (((j) >> 3) & 3))) * 8 + ((j) & 7))
    const int zo0 = b_0 * ZSTR + j_0, ho0 = HOFF(b_0, j_0), hw0 = b_0 * H + j_0;
    const int zo1 = b_1 * ZSTR + j_1, ho1 = HOFF(b_1, j_1), hw1 = b_1 * H + j_1;
    const int zo2 = b_2 * ZSTR + j_2, ho2 = HOFF(b_2, j_2), hw2 = b_2 * H + j_2;
    const int zo3 = b_3 * ZSTR + j_3, ho3 = HOFF(b_3, j_3), hw3 = b_3 * H + j_3;
    float c0 = 0.f, c1 = 0.f, c2 = 0.f, c3 = 0.f;

    // zero h fragments (k>=100 padding stays zero forever)
    for (int i = tid; i < 2048; i += 512) hl[i] = 0;

    // ---- seq staging: lane = row ln15, feats lg*8..+7 and 32+lg*8..+7
    const float* sp = seq + (size_t)(b0 + ln15) * (T_LEN * F_IN) + lg * 8;
    f32x4 s0 = *(const f32x4*)(sp);
    f32x4 s1 = *(const f32x4*)(sp + 4);
    f32x4 s2 = *(const f32x4*)(sp + 32);
    f32x4 s3 = *(const f32x4*)(sp + 36);
    sp += F_IN;

    // prologue: accX = bias + x(0)@Wk
    f32x4 accX[4];
    {
        union { unsigned u[4]; bf16x8 v; } ua, ub;
        ua.u[0] = cvtpk(s0[0], s0[1]); ua.u[1] = cvtpk(s0[2], s0[3]);
        ua.u[2] = cvtpk(s1[0], s1[1]); ua.u[3] = cvtpk(s1[2], s1[3]);
        ub.u[0] = cvtpk(s2[0], s2[1]); ub.u[1] = cvtpk(s2[2], s2[3]);
        ub.u[2] = cvtpk(s3[0], s3[1]); ub.u[3] = cvtpk(s3[2], s3[3]);
        bf16x8 a0 = ua.v, a1 = ub.v;
#pragma unroll
        for (int q = 0; q < 3; q++) {
            f32x4 x = { blf[q], blf[q], blf[q], blf[q] };
            x = __builtin_amdgcn_mfma_f32_16x16x32_bf16(a0, wkf[q][0], x, 0, 0, 0);
            x = __builtin_amdgcn_mfma_f32_16x16x32_bf16(a1, wkf[q][1], x, 0, 0, 0);
            accX[q] = x;
        }
        accX[3] = (f32x4){ blf[3], blf[3], blf[3], blf[3] };
        if (w7) {
            accX[3] = __builtin_amdgcn_mfma_f32_16x16x32_bf16(a0, wkf[3][0], accX[3], 0, 0, 0);
            accX[3] = __builtin_amdgcn_mfma_f32_16x16x32_bf16(a1, wkf[3][1], accX[3], 0, 0, 0);
        }
    }
    // issue load of x(1)
    s0 = *(const f32x4*)(sp);
    s1 = *(const f32x4*)(sp + 4);
    s2 = *(const f32x4*)(sp + 32);
    s3 = *(const f32x4*)(sp + 36);
    sp += F_IN;

    const unsigned short* hp = hl + lane * 8;
    __syncthreads();   // hl zeros visible

    for (int t = 0; t < T_LEN; t++) {
        const bool notlast = (t < T_LEN - 1);
        const bool last = !notlast;

        // ---------- phase 1: accR = accX + h(t-1)@Wr ----------
        bf16x8 hf0 = *(const bf16x8*)(hp);
        bf16x8 hf1 = *(const bf16x8*)(hp + 512);
        bf16x8 hf2 = *(const bf16x8*)(hp + 1024);
        bf16x8 hf3 = *(const bf16x8*)(hp + 1536);

        // cvt x(t+1) (VALU, overlaps hf read latency)
        bf16x8 a0n = {}, a1n = {};
        if (notlast) {
            union { unsigned u[4]; bf16x8 v; } ua, ub;
            ua.u[0] = cvtpk(s0[0], s0[1]); ua.u[1] = cvtpk(s0[2], s0[3]);
            ua.u[2] = cvtpk(s1[0], s1[1]); ua.u[3] = cvtpk(s1[2], s1[3]);
            ub.u[0] = cvtpk(s2[0], s2[1]); ub.u[1] = cvtpk(s2[2], s2[3]);
            ub.u[2] = cvtpk(s3[0], s3[1]); ub.u[3] = cvtpk(s3[2], s3[3]);
            a0n = ua.v; a1n = ub.v;
        }

        f32x4 rr[4];
#pragma unroll
        for (int q = 0; q < 3; q++) rr[q] = accX[q];
        rr[3] = accX[3];
#pragma unroll
        for (int q = 0; q < 3; q++) rr[q] = __builtin_amdgcn_mfma_f32_16x16x32_bf16(hf0, wrf[q][0], rr[q], 0, 0, 0);
        if (w7) rr[3] = __builtin_amdgcn_mfma_f32_16x16x32_bf16(hf0, wrf[3][0], rr[3], 0, 0, 0);
#pragma unroll
        for (int q = 0; q < 3; q++) rr[q] = __builtin_amdgcn_mfma_f32_16x16x32_bf16(hf1, wrf[q][1], rr[q], 0, 0, 0);
        if (w7) rr[3] = __builtin_amdgcn_mfma_f32_16x16x32_bf16(hf1, wrf[3][1], rr[3], 0, 0, 0);
#pragma unroll
        for (int q = 0; q < 3; q++) rr[q] = __builtin_amdgcn_mfma_f32_16x16x32_bf16(hf2, wrf[q][2], rr[q], 0, 0, 0);
        if (w7) rr[3] = __builtin_amdgcn_mfma_f32_16x16x32_bf16(hf2, wrf[3][2], rr[3], 0, 0, 0);
#pragma unroll
        for (int q = 0; q < 3; q++) rr[q] = __builtin_amdgcn_mfma_f32_16x16x32_bf16(hf3, wrf[q][3], rr[q], 0, 0, 0);
        if (w7) rr[3] = __builtin_amdgcn_mfma_f32_16x16x32_bf16(hf3, wrf[3][3], rr[3], 0, 0, 0);

        // prefetch x(t+2) (in flight across the rest of this step)
        if (t < T_LEN - 2) {
            s0 = *(const f32x4*)(sp);
            s1 = *(const f32x4*)(sp + 4);
            s2 = *(const f32x4*)(sp + 32);
            s3 = *(const f32x4*)(sp + 36);
            sp += F_IN;
        }

        // scatter z: D-frag row = lg*4+r, col = tile*16 + ln15  (2-way banks, free)
        {
            float* zr = zb + (lg * 4) * ZSTR + ln15;
#pragma unroll
            for (int q = 0; q < 3; q++) {
                const int col = (nt0 + q) * 16;
#pragma unroll
                for (int r4 = 0; r4 < 4; r4++) zr[r4 * ZSTR + col] = rr[q][r4];
            }
            if (w7) {
#pragma unroll
                for (int r4 = 0; r4 < 4; r4++) zr[r4 * ZSTR + 24 * 16] = rr[3][r4];
            }
        }
        __syncthreads();   // B1: z visible

        // ---------- phase 2: gate VALU  ||  accX = bias + x(t+1)@Wk ----------
        // hoisted z reads (latency hidden under MFMA-X)
        float z0i = zb[zo0], z0f = zb[zo0 + H], z0g = zb[zo0 + 2 * H], z0o = zb[zo0 + 3 * H];
        float z1i = zb[zo1], z1f = zb[zo1 + H], z1g = zb[zo1 + 2 * H], z1o = zb[zo1 + 3 * H];
        float z2i = zb[zo2], z2f = zb[zo2 + H], z2g = zb[zo2 + 2 * H], z2o = zb[zo2 + 3 * H];
        float z3i = 0, z3f = 0, z3g = 0, z3o = 0;
        if (w0) { z3i = zb[zo3]; z3f = zb[zo3 + H]; z3g = zb[zo3 + 2 * H]; z3o = zb[zo3 + 3 * H]; }

        if (notlast) {
#pragma unroll
            for (int q = 0; q < 3; q++) {
                f32x4 x = { blf[q], blf[q], blf[q], blf[q] };
                x = __builtin_amdgcn_mfma_f32_16x16x32_bf16(a0n, wkf[q][0], x, 0, 0, 0);
                x = __builtin_amdgcn_mfma_f32_16x16x32_bf16(a1n, wkf[q][1], x, 0, 0, 0);
                accX[q] = x;
            }
            if (w7) {
                f32x4 x = { blf[3], blf[3], blf[3], blf[3] };
                x = __builtin_amdgcn_mfma_f32_16x16x32_bf16(a0n, wkf[3][0], x, 0, 0, 0);
                x = __builtin_amdgcn_mfma_f32_16x16x32_bf16(a1n, wkf[3][1], x, 0, 0, 0);
                accX[3] = x;
            }
        }

#define DOGATE(ZI, ZF, ZG, ZO, CREG, HO, HW) do {                   \
            float _i = sigm(ZI), _f = sigm(ZF), _o = sigm(ZO);      \
            float _g = fmaxf(ZG, 0.0f);                             \
            CREG = _f * CREG + _i * _g;                             \
            float _h = _o * fmaxf(CREG, 0.0f);                      \
            hl[HO] = f2bf(_h);                                      \
            if (last) h32[HW] = _h;                                 \
        } while (0)

        DOGATE(z0i, z0f, z0g, z0o, c0, ho0, hw0);
        DOGATE(z1i, z1f, z1g, z1o, c1, ho1, hw1);
        DOGATE(z2i, z2f, z2g, z2o, c2, ho2, hw2);
        if (w0) DOGATE(z3i, z3f, z3g, z3o, c3, ho3, hw3);

        __syncthreads();   // B2: h frags visible
    }

    // ---- epilogue: fp32 dense chain + softmax ----
    float* att  = (float*)smem;            // [16][128]
    float* catb = (float*)(smem + 8192);   // [16][200]
    float* x1b  = (float*)(smem + 20992);  // [16][100]
    float* x2b  = (float*)smem;            // [16][50]
    float* lgb  = (float*)(smem + 3200);   // [16][10]

    {
        const f32x4* src = (const f32x4*)(attrs + (size_t)b0 * A_IN);
        ((f32x4*)att)[tid] = src[tid];     // 16x128 floats
    }
    __syncthreads();

#pragma unroll
    for (int k = 0; k < 4; k++) {
        int e = tid + 512 * k;
        if (e < ROWS * H) {
            int b = e & 15, j = e >> 4;
            float s = bd[j];
            for (int kk = 0; kk < A_IN; kk++) s += att[b * A_IN + kk] * Wd[kk * H + j];
            catb[b * 200 + j] = fmaxf(s, 0.0f);
            catb[b * 200 + H + j] = h32[b * H + j];
        }
    }
    __syncthreads();

#pragma unroll
    for (int k = 0; k < 4; k++) {
        int e = tid + 512 * k;
        if (e < ROWS * H) {
            int b = e & 15, j = e >> 4;
            float s = b1[j];
            for (int kk = 0; kk < 200; kk++) s += catb[b * 200 + kk] * W1[kk * H + j];
            x1b[b * H + j] = fmaxf(s, 0.0f);
        }
    }
    __syncthreads();

#pragma unroll
    for (int k = 0; k < 2; k++) {
        int e = tid + 512 * k;
        if (e < ROWS * 50) {
            int b = e & 15, j = e >> 4;
            float s = b2[j];
            for (int kk = 0; kk < H; kk++) s += x1b[b * H + kk] * W2[kk * 50 + j];
            x2b[b * 50 + j] = fmaxf(s, 0.0f);
        }
    }
    __syncthreads();

    if (tid < ROWS * OUT_N) {
        int b = tid / OUT_N, o = tid % OUT_N;
        float s = bc[o];
        for (int kk = 0; kk < 50; kk++) s += x2b[b * 50 + kk] * Wc[kk * OUT_N + o];
        lgb[b * OUT_N + o] = s;
    }
    __syncthreads();

    if (tid < ROWS) {
        int b = tid;
        float m = -1e30f, v[10];
#pragma unroll
        for (int o = 0; o < 10; o++) { v[o] = lgb[b * 10 + o]; m = fmaxf(m, v[o]); }
        float ssum = 0.0f;
#pragma unroll
        for (int o = 0; o < 10; o++) { v[o] = __expf(v[o] - m); ssum += v[o]; }
        float inv = 1.0f / ssum;
#pragma unroll
        for (int o = 0; o < 10; o++) out[(size_t)(b0 + b) * 10 + o] = v[o] * inv;
    }
}

extern "C" void kernel_launch(void* const* d_in, const int* in_sizes, int n_in,
                              void* d_out, int out_size, void* d_ws, size_t ws_size,
                              hipStream_t stream) {
    const float* attrs = (const float*)d_in[0];
    const float* seq   = (const float*)d_in[1];
    const float* Wd    = (const float*)d_in[2];
    const float* bd    = (const float*)d_in[3];
    const float* Wk    = (const float*)d_in[4];
    const float* Wr    = (const float*)d_in[5];
    const float* bl    = (const float*)d_in[6];
    const float* W1    = (const float*)d_in[7];
    const float* b1    = (const float*)d_in[8];
    const float* W2    = (const float*)d_in[9];
    const float* b2    = (const float*)d_in[10];
    const float* Wc    = (const float*)d_in[11];
    const float* bc    = (const float*)d_in[12];
    float* out = (float*)d_out;

    hipLaunchKernelGGL(traj_kernel, dim3(256), dim3(512), 0, stream,
                       attrs, seq, Wd, bd, Wk, Wr, bl, W1, b1, W2, b2, Wc, bc, out);
}

// Round 4
// 285.788 us; speedup vs baseline: 5.8668x; 1.2726x over previous
//
#include <hip/hip_runtime.h>
#include <hip/hip_bf16.h>

#define T_LEN 200
#define F_IN 64
#define A_IN 128
#define H 100
#define H4 400
#define OUT_N 10
#define ROWS 16

typedef __attribute__((ext_vector_type(8))) short bf16x8;
typedef __attribute__((ext_vector_type(4))) float f32x4;

__device__ __forceinline__ unsigned short f2bf(float f) {
    union { float f; unsigned u; } v; v.f = f;
    unsigned r = v.u + 0x7FFFu + ((v.u >> 16) & 1u);
    return (unsigned short)(r >> 16);
}

// 2x f32 -> packed bf16 (RNE), single instruction
__device__ __forceinline__ unsigned cvtpk(float lo, float hi) {
    unsigned r;
    asm("v_cvt_pk_bf16_f32 %0, %1, %2" : "=v"(r) : "v"(lo), "v"(hi));
    return r;
}

__device__ __forceinline__ float sigm(float x) {
    return 1.0f / (1.0f + __expf(-x));
}

// h fragment slot for (batch b, hidden j): B-frag col=lane&15=b, k=lg*8+i
#define HOFF(b, j) ((((j) >> 5) * 64 + ((b) + 16 * (((j) >> 3) & 3))) * 8 + ((j) & 7))

extern "C" __global__ void __launch_bounds__(512, 2)
traj_kernel(const float* __restrict__ attrs, const float* __restrict__ seq,
            const float* __restrict__ Wd, const float* __restrict__ bd,
            const float* __restrict__ Wk, const float* __restrict__ Wr,
            const float* __restrict__ bl, const float* __restrict__ W1,
            const float* __restrict__ b1, const float* __restrict__ W2,
            const float* __restrict__ b2, const float* __restrict__ Wc,
            const float* __restrict__ bc, float* __restrict__ out)
{
    // LDS map (bytes), total 27648:
    //   [0, 8192)       hlb  ushort[2][2048]  h bf16 B-frag double buffer
    //   [8192, 14592)   h32  float[16][100]   final h fp32
    // epilogue aliases (loop-dead regions):
    //   att [16][128]@0, catb [16][200]@14592, x1b [16][100]@0,
    //   x2b [16][50]@8192, lgb [16][10]@11392
    __shared__ __align__(16) char smem[27648];
    unsigned short* hl = (unsigned short*)smem;
    float* h32 = (float*)(smem + 8192);

    const int tid = threadIdx.x;
    const int lane = tid & 63;
    const int w = tid >> 6;
    const int ln15 = lane & 15;
    const int lg = lane >> 4;
    const int b0 = blockIdx.x * ROWS;

    // output-dim tiles (Z^T rows): waves 0..6 own {3w..3w+2}; wave 7 owns {21..24}
    const int nt0 = 3 * w;
    const int ntc = (w == 7) ? 4 : 3;
    const bool w7 = (w == 7);

    // ---- one-time weight A-fragment packing, with gate-interleaved column perm ----
    // A-frag (16x16x32): lane holds row m = lane&15, k = (lane>>4)*8 + i.
    // Permuted row p = tile*16 + m maps to original column c = (tile*4 + (m>>2)) + 100*(m&3),
    // so D rows lg*4+r of a lane are gates r=i,f,g,o of hidden j = tile*4+lg.
    bf16x8 wkf[4][2];
    bf16x8 wrf[4][4];
    f32x4 blf[4];
    const int rw = ln15 & 3;          // gate index of this lane's A rows
    const int qr = ln15 >> 2;         // j sub-index
#pragma unroll
    for (int q = 0; q < 4; q++) {
        const bool v = (q < ntc);
        const int tile = nt0 + q;
        const int c = v ? (tile * 4 + qr) + 100 * rw : 0;
#pragma unroll
        for (int kt = 0; kt < 2; kt++) {
            bf16x8 f;
#pragma unroll
            for (int i = 0; i < 8; i++) {
                int k = kt * 32 + lg * 8 + i;
                f[i] = (short)f2bf(v ? Wk[k * H4 + c] : 0.0f);
            }
            wkf[q][kt] = f;
        }
#pragma unroll
        for (int kt = 0; kt < 4; kt++) {
            bf16x8 f;
#pragma unroll
            for (int i = 0; i < 8; i++) {
                int k = kt * 32 + lg * 8 + i;
                f[i] = (short)f2bf((v && k < H) ? Wr[k * H4 + c] : 0.0f);
            }
            wrf[q][kt] = f;
        }
        // bias vector for this lane's gate quad: j = tile*4 + lg
        int j = tile * 4 + lg;
        if (v) blf[q] = (f32x4){ bl[j], bl[H + j], bl[2 * H + j], bl[3 * H + j] };
        else   blf[q] = (f32x4){ 0.f, 0.f, 0.f, 0.f };
    }

    // gate destinations: batch b = ln15, hidden j_q = (nt0+q)*4 + lg
    int hoq[4], h32q[4];
#pragma unroll
    for (int q = 0; q < 4; q++) {
        int j = (nt0 + q) * 4 + lg;
        if (j > 99) j = 99;  // inactive q only
        hoq[q] = HOFF(ln15, j);
        h32q[q] = ln15 * H + j;
    }
    float cr0 = 0.f, cr1 = 0.f, cr2 = 0.f, cr3 = 0.f;

    // zero both h buffers (padding k>=100 stays zero forever)
    for (int i = tid; i < 4096; i += 512) hl[i] = 0;

    // ---- seq staging: lane = batch row ln15, feats lg*8..+7 and 32+lg*8..+7 ----
    const float* sp = seq + (size_t)(b0 + ln15) * (T_LEN * F_IN) + lg * 8;
    f32x4 s0 = *(const f32x4*)(sp);
    f32x4 s1 = *(const f32x4*)(sp + 4);
    f32x4 s2 = *(const f32x4*)(sp + 32);
    f32x4 s3 = *(const f32x4*)(sp + 36);
    sp += F_IN;

    // prologue: accX = bias + x(0)@Wk^T   (accX[q] holds gates-quad pre-activation)
    f32x4 accX[4];
    {
        union { unsigned u[4]; bf16x8 v; } ua, ub;
        ua.u[0] = cvtpk(s0[0], s0[1]); ua.u[1] = cvtpk(s0[2], s0[3]);
        ua.u[2] = cvtpk(s1[0], s1[1]); ua.u[3] = cvtpk(s1[2], s1[3]);
        ub.u[0] = cvtpk(s2[0], s2[1]); ub.u[1] = cvtpk(s2[2], s2[3]);
        ub.u[2] = cvtpk(s3[0], s3[1]); ub.u[3] = cvtpk(s3[2], s3[3]);
        bf16x8 a0 = ua.v, a1 = ub.v;
#pragma unroll
        for (int q = 0; q < 3; q++) {
            f32x4 x = __builtin_amdgcn_mfma_f32_16x16x32_bf16(wkf[q][0], a0, blf[q], 0, 0, 0);
            accX[q] = __builtin_amdgcn_mfma_f32_16x16x32_bf16(wkf[q][1], a1, x, 0, 0, 0);
        }
        if (w7) {
            f32x4 x = __builtin_amdgcn_mfma_f32_16x16x32_bf16(wkf[3][0], a0, blf[3], 0, 0, 0);
            accX[3] = __builtin_amdgcn_mfma_f32_16x16x32_bf16(wkf[3][1], a1, x, 0, 0, 0);
        }
    }
    // issue load of x(1)
    s0 = *(const f32x4*)(sp);
    s1 = *(const f32x4*)(sp + 4);
    s2 = *(const f32x4*)(sp + 32);
    s3 = *(const f32x4*)(sp + 36);
    sp += F_IN;

    __syncthreads();   // hl zeros visible

    for (int t = 0; t < T_LEN; t++) {
        const bool notlast = (t < T_LEN - 1);
        const bool last = !notlast;

        // ---- read h(t-1) B-frags from buf[t&1] (conflict-free b128) ----
        const unsigned short* hp = hl + ((t & 1) << 11) + lane * 8;
        bf16x8 hf0 = *(const bf16x8*)(hp);
        bf16x8 hf1 = *(const bf16x8*)(hp + 512);
        bf16x8 hf2 = *(const bf16x8*)(hp + 1024);
        bf16x8 hf3 = *(const bf16x8*)(hp + 1536);

        // cvt x(t+1) (overlaps h-frag read latency)
        bf16x8 a0n = {}, a1n = {};
        if (notlast) {
            union { unsigned u[4]; bf16x8 v; } ua, ub;
            ua.u[0] = cvtpk(s0[0], s0[1]); ua.u[1] = cvtpk(s0[2], s0[3]);
            ua.u[2] = cvtpk(s1[0], s1[1]); ua.u[3] = cvtpk(s1[2], s1[3]);
            ub.u[0] = cvtpk(s2[0], s2[1]); ub.u[1] = cvtpk(s2[2], s2[3]);
            ub.u[2] = cvtpk(s3[0], s3[1]); ub.u[3] = cvtpk(s3[2], s3[3]);
            a0n = ua.v; a1n = ub.v;
        }

        // ---- rr = accX + h(t-1)@Wr^T : per-lane gate quads land in rr[q] ----
        f32x4 rr[4];
#pragma unroll
        for (int q = 0; q < 3; q++)
            rr[q] = __builtin_amdgcn_mfma_f32_16x16x32_bf16(wrf[q][0], hf0, accX[q], 0, 0, 0);
        if (w7)
            rr[3] = __builtin_amdgcn_mfma_f32_16x16x32_bf16(wrf[3][0], hf0, accX[3], 0, 0, 0);
#pragma unroll
        for (int q = 0; q < 3; q++)
            rr[q] = __builtin_amdgcn_mfma_f32_16x16x32_bf16(wrf[q][1], hf1, rr[q], 0, 0, 0);
        if (w7)
            rr[3] = __builtin_amdgcn_mfma_f32_16x16x32_bf16(wrf[3][1], hf1, rr[3], 0, 0, 0);
#pragma unroll
        for (int q = 0; q < 3; q++)
            rr[q] = __builtin_amdgcn_mfma_f32_16x16x32_bf16(wrf[q][2], hf2, rr[q], 0, 0, 0);
        if (w7)
            rr[3] = __builtin_amdgcn_mfma_f32_16x16x32_bf16(wrf[3][2], hf2, rr[3], 0, 0, 0);
#pragma unroll
        for (int q = 0; q < 3; q++)
            rr[q] = __builtin_amdgcn_mfma_f32_16x16x32_bf16(wrf[q][3], hf3, rr[q], 0, 0, 0);
        if (w7)
            rr[3] = __builtin_amdgcn_mfma_f32_16x16x32_bf16(wrf[3][3], hf3, rr[3], 0, 0, 0);

        // prefetch x(t+2)
        if (t < T_LEN - 2) {
            s0 = *(const f32x4*)(sp);
            s1 = *(const f32x4*)(sp + 4);
            s2 = *(const f32x4*)(sp + 32);
            s3 = *(const f32x4*)(sp + 36);
            sp += F_IN;
        }

        // ---- gates entirely in registers; write h(t) bf16 to buf[(t+1)&1] ----
        unsigned short* hwp = hl + (((t + 1) & 1) << 11);

#define DOGATE(RRQ, CR, HO, HW) do {                                  \
            float _i = sigm(RRQ[0]), _f = sigm(RRQ[1]);               \
            float _g = fmaxf(RRQ[2], 0.0f), _o = sigm(RRQ[3]);        \
            CR = _f * CR + _i * _g;                                   \
            float _h = _o * fmaxf(CR, 0.0f);                          \
            hwp[HO] = (unsigned short)cvtpk(_h, _h);                  \
            if (last) h32[HW] = _h;                                   \
        } while (0)

        DOGATE(rr[0], cr0, hoq[0], h32q[0]);
        DOGATE(rr[1], cr1, hoq[1], h32q[1]);
        DOGATE(rr[2], cr2, hoq[2], h32q[2]);
        if (w7) DOGATE(rr[3], cr3, hoq[3], h32q[3]);

        // ---- accX = bias + x(t+1)@Wk^T (MFMA pipe, overlaps gate VALU) ----
        if (notlast) {
#pragma unroll
            for (int q = 0; q < 3; q++) {
                f32x4 x = __builtin_amdgcn_mfma_f32_16x16x32_bf16(wkf[q][0], a0n, blf[q], 0, 0, 0);
                accX[q] = __builtin_amdgcn_mfma_f32_16x16x32_bf16(wkf[q][1], a1n, x, 0, 0, 0);
            }
            if (w7) {
                f32x4 x = __builtin_amdgcn_mfma_f32_16x16x32_bf16(wkf[3][0], a0n, blf[3], 0, 0, 0);
                accX[3] = __builtin_amdgcn_mfma_f32_16x16x32_bf16(wkf[3][1], a1n, x, 0, 0, 0);
            }
        }

        __syncthreads();   // single barrier: h(t) visible; protects buf WAR
    }

    // ---- epilogue: fp32 dense chain + softmax ----
    float* att  = (float*)smem;             // [16][128]
    float* catb = (float*)(smem + 14592);   // [16][200]
    float* x1b  = (float*)smem;             // [16][100]
    float* x2b  = (float*)(smem + 8192);    // [16][50]
    float* lgb  = (float*)(smem + 11392);   // [16][10]

    {
        const f32x4* src = (const f32x4*)(attrs + (size_t)b0 * A_IN);
        ((f32x4*)att)[tid] = src[tid];      // 16x128 floats
    }
    __syncthreads();

#pragma unroll
    for (int k = 0; k < 4; k++) {
        int e = tid + 512 * k;
        if (e < ROWS * H) {
            int b = e & 15, j = e >> 4;
            float s = bd[j];
            for (int kk = 0; kk < A_IN; kk++) s += att[b * A_IN + kk] * Wd[kk * H + j];
            catb[b * 200 + j] = fmaxf(s, 0.0f);
            catb[b * 200 + H + j] = h32[b * H + j];
        }
    }
    __syncthreads();

#pragma unroll
    for (int k = 0; k < 4; k++) {
        int e = tid + 512 * k;
        if (e < ROWS * H) {
            int b = e & 15, j = e >> 4;
            float s = b1[j];
            for (int kk = 0; kk < 200; kk++) s += catb[b * 200 + kk] * W1[kk * H + j];
            x1b[b * H + j] = fmaxf(s, 0.0f);
        }
    }
    __syncthreads();

#pragma unroll
    for (int k = 0; k < 2; k++) {
        int e = tid + 512 * k;
        if (e < ROWS * 50) {
            int b = e & 15, j = e >> 4;
            float s = b2[j];
            for (int kk = 0; kk < H; kk++) s += x1b[b * H + kk] * W2[kk * 50 + j];
            x2b[b * 50 + j] = fmaxf(s, 0.0f);
        }
    }
    __syncthreads();

    if (tid < ROWS * OUT_N) {
        int b = tid / OUT_N, o = tid % OUT_N;
        float s = bc[o];
        for (int kk = 0; kk < 50; kk++) s += x2b[b * 50 + kk] * Wc[kk * OUT_N + o];
        lgb[b * OUT_N + o] = s;
    }
    __syncthreads();

    if (tid < ROWS) {
        int b = tid;
        float m = -1e30f, v[10];
#pragma unroll
        for (int o = 0; o < 10; o++) { v[o] = lgb[b * 10 + o]; m = fmaxf(m, v[o]); }
        float ssum = 0.0f;
#pragma unroll
        for (int o = 0; o < 10; o++) { v[o] = __expf(v[o] - m); ssum += v[o]; }
        float inv = 1.0f / ssum;
#pragma unroll
        for (int o = 0; o < 10; o++) out[(size_t)(b0 + b) * 10 + o] = v[o] * inv;
    }
}

extern "C" void kernel_launch(void* const* d_in, const int* in_sizes, int n_in,
                              void* d_out, int out_size, void* d_ws, size_t ws_size,
                              hipStream_t stream) {
    const float* attrs = (const float*)d_in[0];
    const float* seq   = (const float*)d_in[1];
    const float* Wd    = (const float*)d_in[2];
    const float* bd    = (const float*)d_in[3];
    const float* Wk    = (const float*)d_in[4];
    const float* Wr    = (const float*)d_in[5];
    const float* bl    = (const float*)d_in[6];
    const float* W1    = (const float*)d_in[7];
    const float* b1    = (const float*)d_in[8];
    const float* W2    = (const float*)d_in[9];
    const float* b2    = (const float*)d_in[10];
    const float* Wc    = (const float*)d_in[11];
    const float* bc    = (const float*)d_in[12];
    float* out = (float*)d_out;

    hipLaunchKernelGGL(traj_kernel, dim3(256), dim3(512), 0, stream,
                       attrs, seq, Wd, bd, Wk, Wr, bl, W1, b1, W2, b2, Wc, bc, out);
}